// Round 7
// baseline (5096.388 us; speedup 1.0000x reference)
//
#include <hip/hip_runtime.h>
#include <stdint.h>

#define B_ 64
#define T_ 2048
#define F_ 128
#define H_ 256
#define TC_ 1022

typedef __bf16 bf16x8 __attribute__((ext_vector_type(8)));
typedef float f32x4 __attribute__((ext_vector_type(4)));
typedef unsigned long long u64;

__device__ __forceinline__ ushort f2bf(float f) {
    uint32_t u = __builtin_bit_cast(uint32_t, f);
    u += 0x7FFFu + ((u >> 16) & 1u);
    return (ushort)(u >> 16);
}
__device__ __forceinline__ float sigmoidf_(float x) {
    return __builtin_amdgcn_rcpf(1.f + __expf(-x));
}
__device__ __forceinline__ float tanhf_(float x) {
    x = fminf(15.f, fmaxf(-15.f, x));
    float e = __expf(2.f * x);
    return 1.f - 2.f * __builtin_amdgcn_rcpf(e + 1.f);
}

// ---- Kernel 1: sum of squares over T for F.normalize(dim=1) ----
__global__ __launch_bounds__(128) void k_sqsum(const float* __restrict__ in,
                                               float* __restrict__ sq) {
    int b = blockIdx.x >> 4, tq = blockIdx.x & 15, f = threadIdx.x;
    const float* p = in + ((size_t)b * T_ + (size_t)tq * 128) * F_ + f;
    float acc = 0.f;
#pragma unroll 8
    for (int t = 0; t < 128; ++t) { float v = p[(size_t)t * F_]; acc += v * v; }
    atomicAdd(&sq[b * F_ + f], acc);
}

// ---- Kernel 2: weight repack to bf16 block-row order; bias combine ----
// wbf[g2][m][k]: g2 = unit>>2 (0..63), m = uu*4+gate, k: [0,64)=w_ih, [64,320)=w_hh
__global__ __launch_bounds__(256) void k_prep(const float* __restrict__ wih, const float* __restrict__ whh,
                                              const float* __restrict__ bih, const float* __restrict__ bhh,
                                              ushort* __restrict__ wbf, float* __restrict__ bias) {
    int e = blockIdx.x * 256 + threadIdx.x;
    if (e < 64 * 16 * 320) {
        int g = e / 5120, m = (e / 320) & 15, k = e % 320;
        int j = (m & 3) * 256 + g * 4 + (m >> 2);  // gate*256 + unit
        float v = (k < 64) ? wih[j * 64 + k] : whh[j * 256 + (k - 64)];
        wbf[e] = f2bf(v);
    }
    if (e < 1024) bias[e] = bih[e] + bhh[e];
}

// ---- Kernel 3: fused normalize + conv1d(K=5,S=2) + bias + relu -> li bf16 [tc][b][72pad] ----
__global__ __launch_bounds__(256) void k_conv(const float* __restrict__ in, const float* __restrict__ cw,
                                              const float* __restrict__ cb, const float* __restrict__ sq,
                                              ushort* __restrict__ li) {
    __shared__ float rn[128];
    __shared__ __align__(16) float xs[67 * 129];
    __shared__ __align__(16) float wl[80 * 68];
    int b = blockIdx.x >> 5, tile = blockIdx.x & 31;
    int tc0 = tile * 32;
    int tid = threadIdx.x;
    if (tid < 128) { float ss = sq[b * 128 + tid]; rn[tid] = 1.f / fmaxf(sqrtf(ss), 1e-12f); }
    __syncthreads();
    const float* ip = in + ((size_t)b * T_ + (size_t)(2 * tc0)) * F_;
    for (int i = tid; i < 67 * 128; i += 256) {
        int r = i >> 7, f = i & 127;
        int t = 2 * tc0 + r;
        xs[r * 129 + f] = (t < T_) ? ip[(size_t)r * F_ + f] * rn[f] : 0.f;
    }
    int cg = tid & 15, tcg = tid >> 4;
    float a00 = 0, a01 = 0, a10 = 0, a11 = 0, a20 = 0, a21 = 0, a30 = 0, a31 = 0;
    for (int fc = 0; fc < 8; ++fc) {
        __syncthreads();
        for (int i = tid; i < 64 * 80; i += 256) {
            int c = i / 80, j = i - c * 80;
            wl[j * 68 + c] = cw[c * 640 + fc * 80 + j];
        }
        __syncthreads();
#pragma unroll
        for (int fi = 0; fi < 16; ++fi) {
#pragma unroll
            for (int k = 0; k < 5; ++k) {
                const float4 w4 = *(const float4*)&wl[(fi * 5 + k) * 68 + cg * 4];
                float x0 = xs[(4 * tcg + k) * 129 + fc * 16 + fi];
                float x1 = xs[(4 * tcg + 2 + k) * 129 + fc * 16 + fi];
                a00 += w4.x * x0; a01 += w4.x * x1;
                a10 += w4.y * x0; a11 += w4.y * x1;
                a20 += w4.z * x0; a21 += w4.z * x1;
                a30 += w4.w * x0; a31 += w4.w * x1;
            }
        }
    }
    float bc0 = cb[cg * 4 + 0], bc1 = cb[cg * 4 + 1], bc2 = cb[cg * 4 + 2], bc3 = cb[cg * 4 + 3];
#pragma unroll
    for (int tt = 0; tt < 2; ++tt) {
        int tc = tc0 + tcg * 2 + tt;
        if (tc < TC_) {
            float v0 = fmaxf((tt ? a01 : a00) + bc0, 0.f);
            float v1 = fmaxf((tt ? a11 : a10) + bc1, 0.f);
            float v2 = fmaxf((tt ? a21 : a20) + bc2, 0.f);
            float v3 = fmaxf((tt ? a31 : a30) + bc3, 0.f);
            uint2 pk;
            pk.x = (uint32_t)f2bf(v0) | ((uint32_t)f2bf(v1) << 16);
            pk.y = (uint32_t)f2bf(v2) | ((uint32_t)f2bf(v3) << 16);
            *reinterpret_cast<uint2*>(&li[((size_t)tc * 64 + b) * 72 + cg * 4]) = pk;
        }
    }
}

// ---- Kernel 4: pod-structured LSTM scan — L2-LOCAL exchange with MALL fallback.
// R6 post-mortem: placement (p=blockIdx%8 -> same-XCD pods) CONFIRMED by FETCH_SIZE
// 154->40MB (li L2 sharing), but step time barely moved. Conclusion: agent-scope atomics
// are MALL-routed REGARDLESS of placement (R0 atomics == R2 explicit sc0 sc1, within 1%).
// Every version paid 2 serial MALL legs (publish-ACK drained by vmcnt + poll RT) ~= 5-6k cy.
// This version: exchange via PLAIN sc0-only accesses (L1-bypass, served by the XCD's
// shared L2; CDNA vector L1 is write-through, so stores reach the TCC). RT ~200-300 cy.
// Correctness does NOT depend on placement: tagged cells self-validate; on fast-guard
// expiry a block goes BROKEN: republishes its last two parities into a separate MALL
// buffer (agent atomics = R0-proven path) and polls MERGED (per-cell: fast copy if its
// tag matches, else MALL copy). Every wave's poll slice spans all 4 blocks' cells, so a
// bad placement trips ALL waves/blocks into broken mode within ~2 steps (no barrier
// deadlock: fallback needs no sibling barrier progress), converging to R0 (~2.6ms).
// Protocol: cell u64 = (h[2c]|t<<16)|((h[2c+1]|t<<16)<<32), [parity][pod][b:16][c:128];
// parity double-buffer + chain argument bounds intra-pod skew <= 1 (unchanged).
__global__ __launch_bounds__(512) void k_scan(const ushort* __restrict__ li,
                                              const ushort* __restrict__ wbf,
                                              const float* __restrict__ bias,
                                              u64* __restrict__ fastb,
                                              u64* __restrict__ slowb,
                                              float* __restrict__ hfin) {
    __shared__ __align__(16) ushort Hs[16 * 264];  // h [b:16][256+8 pad] bf16, rows 528B
    int p = blockIdx.x & 7, q = blockIdx.x >> 3;
    if (p >= 4) return;                       // only XCDs 0-3 host pods; others exit
    int tid = threadIdx.x;
    int lane = tid & 63, wave = tid >> 6, l16 = lane & 15, quad = lane >> 4;
    int bb = p * 16 + l16;                    // global batch
    int g2a = q * 16 + 2 * wave, g2b = g2a + 1;
    int u0 = g2a * 4 + quad, u1 = g2b * 4 + quad;
    int pc = 32 * q + 4 * wave + (quad >> 1); // publish pair-cell (tile0; tile1 = +2)
    // Stationary A-fragments: two 16-row tiles (rows = l16 within each tile).
    bf16x8 af0[10], af1[10];
    const ushort* wp0 = wbf + ((size_t)(g2a * 16 + l16)) * 320 + quad * 8;
    const ushort* wp1 = wbf + ((size_t)(g2b * 16 + l16)) * 320 + quad * 8;
#pragma unroll
    for (int s = 0; s < 10; ++s) { af0[s] = *(const bf16x8*)(wp0 + s * 32);
                                   af1[s] = *(const bf16x8*)(wp1 + s * 32); }
    float bi0 = bias[u0], bf0 = bias[256 + u0], bg0 = bias[512 + u0], bo0 = bias[768 + u0];
    float bi1 = bias[u1], bf1 = bias[256 + u1], bg1 = bias[512 + u1], bo1 = bias[768 + u1];
    float cs0 = 0.f, cs1 = 0.f;
    bool broken = false;
    u64 lwe0 = ~0ull, lwe1 = ~0ull, lwo0 = ~0ull, lwo1 = ~0ull;  // last-published per parity
    // xt preload for t=0 (B-frags shared by both M-tiles)
    const ushort* xpp = li + ((size_t)0 * 64 + bb) * 72 + quad * 8;
    bf16x8 x0 = *(const bf16x8*)xpp;
    bf16x8 x1 = *(const bf16x8*)(xpp + 32);
#pragma unroll 1
    for (int t = 0; t < TC_; ++t) {
        f32x4 A0 = {0.f, 0.f, 0.f, 0.f}, A1 = {0.f, 0.f, 0.f, 0.f};
        // x-part MFMAs first (xt already in regs from prefetch).
        A0 = __builtin_amdgcn_mfma_f32_16x16x32_bf16(af0[0], x0, A0, 0, 0, 0);
        A1 = __builtin_amdgcn_mfma_f32_16x16x32_bf16(af1[0], x0, A1, 0, 0, 0);
        A0 = __builtin_amdgcn_mfma_f32_16x16x32_bf16(af0[1], x1, A0, 0, 0, 0);
        A1 = __builtin_amdgcn_mfma_f32_16x16x32_bf16(af1[1], x1, A1, 0, 0, 0);
        if (t > 0) {
            uint tg = (uint)(t - 1);
            size_t off = ((size_t)((t - 1) & 1) << 13) + p * 2048 + tid * 4;
            const u64* srcF = fastb + off;
            const u64* srcS = slowb + off;
            u64 vv0, vv1, vv2, vv3;
            bool got = false;
            if (!broken) {
                // FAST poll: plain sc0 loads — L1-bypass, served by the shared XCD L2.
                u64 f0, f1, f2, f3;
                bool ok;
                int guard = 0;
                do {
                    asm volatile(
                        "global_load_dwordx2 %0, %4, off sc0\n\t"
                        "global_load_dwordx2 %1, %4, off offset:8 sc0\n\t"
                        "global_load_dwordx2 %2, %4, off offset:16 sc0\n\t"
                        "global_load_dwordx2 %3, %4, off offset:24 sc0\n\t"
                        "s_waitcnt vmcnt(0)"
                        : "=&v"(f0), "=&v"(f1), "=&v"(f2), "=&v"(f3)
                        : "v"(srcF)
                        : "memory");
                    uint m = (((uint)(f0 >> 16) & 0xFFFFu) ^ tg) | (((uint)(f0 >> 48)) ^ tg);
                    m |= (((uint)(f1 >> 16) & 0xFFFFu) ^ tg) | (((uint)(f1 >> 48)) ^ tg);
                    m |= (((uint)(f2 >> 16) & 0xFFFFu) ^ tg) | (((uint)(f2 >> 48)) ^ tg);
                    m |= (((uint)(f3 >> 16) & 0xFFFFu) ^ tg) | (((uint)(f3 >> 48)) ^ tg);
                    ok = (m == 0);
                } while (!__all(ok) && ++guard < 4096);
                got = __all(ok);
                if (got) { vv0 = f0; vv1 = f1; vv2 = f2; vv3 = f3; }
                else {
                    // Placement assumption failed for this wave -> go broken: republish
                    // our last two parities to the MALL buffer so remote siblings'
                    // merged polls can see them; from now on publish dual.
                    broken = true;
                    if ((quad & 1) == 0) {
                        u64* sE = slowb + p * 2048 + l16 * 128;
                        u64* sO = sE + ((size_t)1 << 13);
                        __hip_atomic_store(sE + pc, lwe0, __ATOMIC_RELAXED, __HIP_MEMORY_SCOPE_AGENT);
                        __hip_atomic_store(sE + pc + 2, lwe1, __ATOMIC_RELAXED, __HIP_MEMORY_SCOPE_AGENT);
                        __hip_atomic_store(sO + pc, lwo0, __ATOMIC_RELAXED, __HIP_MEMORY_SCOPE_AGENT);
                        __hip_atomic_store(sO + pc + 2, lwo1, __ATOMIC_RELAXED, __HIP_MEMORY_SCOPE_AGENT);
                    }
                }
            }
            if (!got) {
                // MERGED poll (broken mode): per cell take fast copy if its tag matches,
                // else the MALL copy. Converges once all pod blocks republish (each does,
                // independently, on its own guard expiry — no cross-block barrier dep).
                u64 f0, f1, f2, f3, s0, s1, s2, s3;
                bool ok;
                int guard = 0;
                do {
                    asm volatile(
                        "global_load_dwordx2 %0, %8, off sc0\n\t"
                        "global_load_dwordx2 %1, %8, off offset:8 sc0\n\t"
                        "global_load_dwordx2 %2, %8, off offset:16 sc0\n\t"
                        "global_load_dwordx2 %3, %8, off offset:24 sc0\n\t"
                        "global_load_dwordx2 %4, %9, off sc0 sc1\n\t"
                        "global_load_dwordx2 %5, %9, off offset:8 sc0 sc1\n\t"
                        "global_load_dwordx2 %6, %9, off offset:16 sc0 sc1\n\t"
                        "global_load_dwordx2 %7, %9, off offset:24 sc0 sc1\n\t"
                        "s_waitcnt vmcnt(0)"
                        : "=&v"(f0), "=&v"(f1), "=&v"(f2), "=&v"(f3),
                          "=&v"(s0), "=&v"(s1), "=&v"(s2), "=&v"(s3)
                        : "v"(srcF), "v"(srcS)
                        : "memory");
                    uint c0 = (((uint)(f0 >> 16) & 0xFFFFu) ^ tg) | (((uint)(f0 >> 48)) ^ tg);
                    uint c1 = (((uint)(f1 >> 16) & 0xFFFFu) ^ tg) | (((uint)(f1 >> 48)) ^ tg);
                    uint c2 = (((uint)(f2 >> 16) & 0xFFFFu) ^ tg) | (((uint)(f2 >> 48)) ^ tg);
                    uint c3 = (((uint)(f3 >> 16) & 0xFFFFu) ^ tg) | (((uint)(f3 >> 48)) ^ tg);
                    vv0 = (c0 == 0) ? f0 : s0;
                    vv1 = (c1 == 0) ? f1 : s1;
                    vv2 = (c2 == 0) ? f2 : s2;
                    vv3 = (c3 == 0) ? f3 : s3;
                    uint m = (((uint)(vv0 >> 16) & 0xFFFFu) ^ tg) | (((uint)(vv0 >> 48)) ^ tg);
                    m |= (((uint)(vv1 >> 16) & 0xFFFFu) ^ tg) | (((uint)(vv1 >> 48)) ^ tg);
                    m |= (((uint)(vv2 >> 16) & 0xFFFFu) ^ tg) | (((uint)(vv2 >> 48)) ^ tg);
                    m |= (((uint)(vv3 >> 16) & 0xFFFFu) ^ tg) | (((uint)(vv3 >> 48)) ^ tg);
                    ok = (m == 0);
                } while (!__all(ok) && ++guard < (1 << 15));
            }
            // Stage to LDS: idx=4*tid -> b=idx>>7, c=idx&127; cell c = units {2c,2c+1}.
            {
                int b = tid >> 5, c0 = (tid * 4) & 127;
                uint4 w;
                w.x = ((uint)vv0 & 0xFFFFu) | (((uint)(vv0 >> 32) & 0xFFFFu) << 16);
                w.y = ((uint)vv1 & 0xFFFFu) | (((uint)(vv1 >> 32) & 0xFFFFu) << 16);
                w.z = ((uint)vv2 & 0xFFFFu) | (((uint)(vv2 >> 32) & 0xFFFFu) << 16);
                w.w = ((uint)vv3 & 0xFFFFu) | (((uint)(vv3 >> 32) & 0xFFFFu) << 16);
                *(uint4*)((char*)Hs + b * 528 + c0 * 4) = w;
            }
            __syncthreads();
            // h-part MFMAs: frag = Hs[row=l16][units s*32+quad*8 ..+8], shared by both tiles.
#pragma unroll
            for (int s = 0; s < 8; ++s) {
                bf16x8 bh = *(const bf16x8*)((const char*)Hs + l16 * 528 + s * 64 + quad * 16);
                A0 = __builtin_amdgcn_mfma_f32_16x16x32_bf16(af0[2 + s], bh, A0, 0, 0, 0);
                A1 = __builtin_amdgcn_mfma_f32_16x16x32_bf16(af1[2 + s], bh, A1, 0, 0, 0);
            }
            __syncthreads();  // frag reads done before next step's staging overwrites Hs
        }
        // Epilogue: lane owns (u0,bb) and (u1,bb).
        float hv0, hv1;
        {
            float gi = A0[0] + bi0, gf = A0[1] + bf0, gg = A0[2] + bg0, go = A0[3] + bo0;
            float ii = sigmoidf_(gi), ff = sigmoidf_(gf), g2 = tanhf_(gg), oo = sigmoidf_(go);
            cs0 = ff * cs0 + ii * g2;
            hv0 = oo * tanhf_(cs0);
        }
        {
            float gi = A1[0] + bi1, gf = A1[1] + bf1, gg = A1[2] + bg1, go = A1[3] + bo1;
            float ii = sigmoidf_(gi), ff = sigmoidf_(gf), g2 = tanhf_(gg), oo = sigmoidf_(go);
            cs1 = ff * cs1 + ii * g2;
            hv1 = oo * tanhf_(cs1);
        }
        if (t == TC_ - 1) {
            hfin[u0 * 64 + bb] = hv0;
            hfin[u1 * 64 + bb] = hv1;
        } else {
            // Publish: pack unit pairs via shfl (quad gets quad+1's value, same l16).
            ushort h0 = f2bf(hv0), h1 = f2bf(hv1);
            uint pr0 = ((uint)h0 & 0xFFFFu) | ((uint)__shfl((int)h0, (lane + 16) & 63) << 16);
            uint pr1 = ((uint)h1 & 0xFFFFu) | ((uint)__shfl((int)h1, (lane + 16) & 63) << 16);
            if ((quad & 1) == 0) {
                uint tg2 = ((uint)t) << 16;
                u64 w0 = (u64)((pr0 & 0xFFFFu) | tg2) | ((u64)((pr0 >> 16) | tg2) << 32);
                u64 w1 = (u64)((pr1 & 0xFFFFu) | tg2) | ((u64)((pr1 >> 16) | tg2) << 32);
                u64* dstF = fastb + ((size_t)(t & 1) << 13) + p * 2048 + l16 * 128;
                // Fast publish: plain sc0 stores -> shared XCD L2 (write-through L1).
                asm volatile(
                    "global_store_dwordx2 %0, %2, off sc0\n\t"
                    "global_store_dwordx2 %1, %3, off sc0"
                    :: "v"(dstF + pc), "v"(dstF + pc + 2), "v"(w0), "v"(w1)
                    : "memory");
                if (broken) {
                    u64* dstS = slowb + ((size_t)(t & 1) << 13) + p * 2048 + l16 * 128;
                    __hip_atomic_store(dstS + pc, w0, __ATOMIC_RELAXED, __HIP_MEMORY_SCOPE_AGENT);
                    __hip_atomic_store(dstS + pc + 2, w1, __ATOMIC_RELAXED, __HIP_MEMORY_SCOPE_AGENT);
                }
                if (t & 1) { lwo0 = w0; lwo1 = w1; } else { lwe0 = w0; lwe1 = w1; }
            }
        }
        // Prefetch next xt (fire after publish; lands during next poll).
        int tn = (t + 1 < TC_) ? t + 1 : t;
        const ushort* xpn = li + ((size_t)tn * 64 + bb) * 72 + quad * 8;
        x0 = *(const bf16x8*)xpn;
        x1 = *(const bf16x8*)(xpn + 32);
    }
}

// ---- Kernel 5: out[b][o] = h_final[:,b] . lin_w[o,:] + lin_b[o] ----
__global__ __launch_bounds__(64) void k_fin(const float* __restrict__ hfin, const float* __restrict__ lw,
                                            const float* __restrict__ lb, float* __restrict__ out) {
    int o = blockIdx.x, b = threadIdx.x;
    float acc = lb[o];
    const float* wp = lw + o * 256;
#pragma unroll 4
    for (int u2 = 0; u2 < 256; ++u2) acc += hfin[u2 * 64 + b] * wp[u2];
    out[b * 10 + o] = acc;
}

extern "C" void kernel_launch(void* const* d_in, const int* in_sizes, int n_in,
                              void* d_out, int out_size, void* d_ws, size_t ws_size,
                              hipStream_t stream) {
    const float* in  = (const float*)d_in[0];
    // d_in[1] ("r") unused
    const float* cw  = (const float*)d_in[2];
    const float* cb  = (const float*)d_in[3];
    const float* wih = (const float*)d_in[4];
    const float* whh = (const float*)d_in[5];
    const float* bih = (const float*)d_in[6];
    const float* bhh = (const float*)d_in[7];
    const float* lw  = (const float*)d_in[8];
    const float* lb  = (const float*)d_in[9];
    float* out = (float*)d_out;

    char* ws = (char*)d_ws;
    float*  sq   = (float*)(ws + 0);          // 32768 B
    u64*    fastb= (u64*)(ws + 32768);        // 131072 B: 2 parity x (4 pods x 2048 cells) x 8B (L2-local)
    float*  bias = (float*)(ws + 163840);     // 4096 B
    float*  hfin = (float*)(ws + 167936);     // 65536 B  [u][b] fp32
    ushort* wbf  = (ushort*)(ws + 233472);    // 655360 B [g2][16][320] bf16
    ushort* li   = (ushort*)(ws + 888832);    // 9418752 B [tc][b][72] bf16
    u64*    slowb= (u64*)(ws + 10307584);     // 131072 B MALL fallback buffer (same layout)

    hipMemsetAsync(sq, 0, 32768, stream);
    hipMemsetAsync(fastb, 0xFF, 131072, stream);  // tag fields -> 0xFFFF, never a valid step
    hipMemsetAsync(slowb, 0xFF, 131072, stream);

    k_sqsum<<<1024, 128, 0, stream>>>(in, sq);
    k_prep<<<1280, 256, 0, stream>>>(wih, whh, bih, bhh, wbf, bias);
    k_conv<<<2048, 256, 0, stream>>>(in, cw, cb, sq, li);
    // 32 blocks: pod p = blockIdx%8 (XCD under round-robin dispatch), q = blockIdx/8.
    // Pods live on XCDs 0-3 (4 same-XCD blocks each); blocks with p>=4 exit at once.
    k_scan<<<32, 512, 0, stream>>>(li, wbf, bias, fastb, slowb, hfin);
    k_fin<<<10, 64, 0, stream>>>(hfin, lw, lb, out);
}

// Round 8
// 2411.026 us; speedup vs baseline: 2.1138x; 2.1138x over previous
//
#include <hip/hip_runtime.h>
#include <stdint.h>

#define B_ 64
#define T_ 2048
#define F_ 128
#define H_ 256
#define TC_ 1022

typedef __bf16 bf16x8 __attribute__((ext_vector_type(8)));
typedef float f32x4 __attribute__((ext_vector_type(4)));
typedef uint u32x4 __attribute__((ext_vector_type(4)));
typedef unsigned long long u64;

__device__ __forceinline__ ushort f2bf(float f) {
    uint32_t u = __builtin_bit_cast(uint32_t, f);
    u += 0x7FFFu + ((u >> 16) & 1u);
    return (ushort)(u >> 16);
}
__device__ __forceinline__ float sigmoidf_(float x) {
    return __builtin_amdgcn_rcpf(1.f + __expf(-x));
}
__device__ __forceinline__ float tanhf_(float x) {
    x = fminf(15.f, fmaxf(-15.f, x));
    float e = __expf(2.f * x);
    return 1.f - 2.f * __builtin_amdgcn_rcpf(e + 1.f);
}

// ---- Kernel 1: sum of squares over T for F.normalize(dim=1) ----
__global__ __launch_bounds__(128) void k_sqsum(const float* __restrict__ in,
                                               float* __restrict__ sq) {
    int b = blockIdx.x >> 4, tq = blockIdx.x & 15, f = threadIdx.x;
    const float* p = in + ((size_t)b * T_ + (size_t)tq * 128) * F_ + f;
    float acc = 0.f;
#pragma unroll 8
    for (int t = 0; t < 128; ++t) { float v = p[(size_t)t * F_]; acc += v * v; }
    atomicAdd(&sq[b * F_ + f], acc);
}

// ---- Kernel 2: weight repack to bf16 block-row order; bias combine ----
// wbf[g2][m][k]: g2 = unit>>2 (0..63), m = uu*4+gate, k: [0,64)=w_ih, [64,320)=w_hh
__global__ __launch_bounds__(256) void k_prep(const float* __restrict__ wih, const float* __restrict__ whh,
                                              const float* __restrict__ bih, const float* __restrict__ bhh,
                                              ushort* __restrict__ wbf, float* __restrict__ bias) {
    int e = blockIdx.x * 256 + threadIdx.x;
    if (e < 64 * 16 * 320) {
        int g = e / 5120, m = (e / 320) & 15, k = e % 320;
        int j = (m & 3) * 256 + g * 4 + (m >> 2);  // gate*256 + unit
        float v = (k < 64) ? wih[j * 64 + k] : whh[j * 256 + (k - 64)];
        wbf[e] = f2bf(v);
    }
    if (e < 1024) bias[e] = bih[e] + bhh[e];
}

// ---- Kernel 3: fused normalize + conv1d(K=5,S=2) + bias + relu -> li bf16 [tc][b][72pad] ----
__global__ __launch_bounds__(256) void k_conv(const float* __restrict__ in, const float* __restrict__ cw,
                                              const float* __restrict__ cb, const float* __restrict__ sq,
                                              ushort* __restrict__ li) {
    __shared__ float rn[128];
    __shared__ __align__(16) float xs[67 * 129];
    __shared__ __align__(16) float wl[80 * 68];
    int b = blockIdx.x >> 5, tile = blockIdx.x & 31;
    int tc0 = tile * 32;
    int tid = threadIdx.x;
    if (tid < 128) { float ss = sq[b * 128 + tid]; rn[tid] = 1.f / fmaxf(sqrtf(ss), 1e-12f); }
    __syncthreads();
    const float* ip = in + ((size_t)b * T_ + (size_t)(2 * tc0)) * F_;
    for (int i = tid; i < 67 * 128; i += 256) {
        int r = i >> 7, f = i & 127;
        int t = 2 * tc0 + r;
        xs[r * 129 + f] = (t < T_) ? ip[(size_t)r * F_ + f] * rn[f] : 0.f;
    }
    int cg = tid & 15, tcg = tid >> 4;
    float a00 = 0, a01 = 0, a10 = 0, a11 = 0, a20 = 0, a21 = 0, a30 = 0, a31 = 0;
    for (int fc = 0; fc < 8; ++fc) {
        __syncthreads();
        for (int i = tid; i < 64 * 80; i += 256) {
            int c = i / 80, j = i - c * 80;
            wl[j * 68 + c] = cw[c * 640 + fc * 80 + j];
        }
        __syncthreads();
#pragma unroll
        for (int fi = 0; fi < 16; ++fi) {
#pragma unroll
            for (int k = 0; k < 5; ++k) {
                const float4 w4 = *(const float4*)&wl[(fi * 5 + k) * 68 + cg * 4];
                float x0 = xs[(4 * tcg + k) * 129 + fc * 16 + fi];
                float x1 = xs[(4 * tcg + 2 + k) * 129 + fc * 16 + fi];
                a00 += w4.x * x0; a01 += w4.x * x1;
                a10 += w4.y * x0; a11 += w4.y * x1;
                a20 += w4.z * x0; a21 += w4.z * x1;
                a30 += w4.w * x0; a31 += w4.w * x1;
            }
        }
    }
    float bc0 = cb[cg * 4 + 0], bc1 = cb[cg * 4 + 1], bc2 = cb[cg * 4 + 2], bc3 = cb[cg * 4 + 3];
#pragma unroll
    for (int tt = 0; tt < 2; ++tt) {
        int tc = tc0 + tcg * 2 + tt;
        if (tc < TC_) {
            float v0 = fmaxf((tt ? a01 : a00) + bc0, 0.f);
            float v1 = fmaxf((tt ? a11 : a10) + bc1, 0.f);
            float v2 = fmaxf((tt ? a21 : a20) + bc2, 0.f);
            float v3 = fmaxf((tt ? a31 : a30) + bc3, 0.f);
            uint2 pk;
            pk.x = (uint32_t)f2bf(v0) | ((uint32_t)f2bf(v1) << 16);
            pk.y = (uint32_t)f2bf(v2) | ((uint32_t)f2bf(v3) << 16);
            *reinterpret_cast<uint2*>(&li[((size_t)tc * 64 + b) * 72 + cg * 4]) = pk;
        }
    }
}

// ---- Kernel 4: pod-structured LSTM scan — ATOMIC publish + PLAIN-sc0 poll, XCD-local.
// Evidence ledger: R6 (atomic store + atomic load, same-XCD): FETCH 154->40MB (polls
// L2-served, placement p=blockIdx%8 co-locates) but step ~5.2k cy. R7 (plain store +
// plain load): fast path invisible after ~1M cy -> gfx950 plain stores do NOT reach the
// shared TCC (write-back L1, unlike CDNA3). Untested quadrant: ATOMIC store (R6-proven
// visible same-XCD) + PLAIN sc0 load (L1-bypass, L2-served, no atomic-path serialization
// at the TCC). Theory: R6's residual is the CONSUMER-side atomic-load path cost repeated
// over ~20 retries/step; swapping only the load instruction removes it.
// Fallback (deadlock-free, trivial): SAME cells, SAME layout — if a wave's fast poll
// guard (1024) expires, it switches (sticky) to the R6 atomic-load poll. Worst case ~= R6.
// Tags live in each 32b half (value 16b | tag 16b) so torn/stale plain reads are
// self-detecting; parity double-buffer + chain argument bound skew <= 1 as ever.
// Hs is DOUBLE-BUFFERED -> single barrier/step (safe: a wave reaches barrier(t+1) only
// after its step-t frag reads, so staging buf[(t+1)&1] never collides with step-(t-1)
// reads of that buffer).
__global__ __launch_bounds__(512) void k_scan(const ushort* __restrict__ li,
                                              const ushort* __restrict__ wbf,
                                              const float* __restrict__ bias,
                                              u64* __restrict__ hbuf,
                                              float* __restrict__ hfin) {
    __shared__ __align__(16) ushort Hs[2][16 * 264];  // dbuf: h [b:16][256+8 pad], rows 528B
    int p = blockIdx.x & 7, q = blockIdx.x >> 3;
    if (p >= 4) return;                       // only XCDs 0-3 host pods; others exit
    int tid = threadIdx.x;
    int lane = tid & 63, wave = tid >> 6, l16 = lane & 15, quad = lane >> 4;
    int bb = p * 16 + l16;                    // global batch
    int g2a = q * 16 + 2 * wave, g2b = g2a + 1;
    int u0 = g2a * 4 + quad, u1 = g2b * 4 + quad;
    int pc = 32 * q + 4 * wave + (quad >> 1); // publish pair-cell (tile0; tile1 = +2)
    // Stationary A-fragments: two 16-row tiles (rows = l16 within each tile).
    bf16x8 af0[10], af1[10];
    const ushort* wp0 = wbf + ((size_t)(g2a * 16 + l16)) * 320 + quad * 8;
    const ushort* wp1 = wbf + ((size_t)(g2b * 16 + l16)) * 320 + quad * 8;
#pragma unroll
    for (int s = 0; s < 10; ++s) { af0[s] = *(const bf16x8*)(wp0 + s * 32);
                                   af1[s] = *(const bf16x8*)(wp1 + s * 32); }
    float bi0 = bias[u0], bf0 = bias[256 + u0], bg0 = bias[512 + u0], bo0 = bias[768 + u0];
    float bi1 = bias[u1], bf1 = bias[256 + u1], bg1 = bias[512 + u1], bo1 = bias[768 + u1];
    float cs0 = 0.f, cs1 = 0.f;
    bool broken = false;
    // xt preload for t=0 (B-frags shared by both M-tiles)
    const ushort* xpp = li + ((size_t)0 * 64 + bb) * 72 + quad * 8;
    bf16x8 x0 = *(const bf16x8*)xpp;
    bf16x8 x1 = *(const bf16x8*)(xpp + 32);
#pragma unroll 1
    for (int t = 0; t < TC_; ++t) {
        f32x4 A0 = {0.f, 0.f, 0.f, 0.f}, A1 = {0.f, 0.f, 0.f, 0.f};
        // x-part MFMAs first (xt already in regs from prefetch).
        A0 = __builtin_amdgcn_mfma_f32_16x16x32_bf16(af0[0], x0, A0, 0, 0, 0);
        A1 = __builtin_amdgcn_mfma_f32_16x16x32_bf16(af1[0], x0, A1, 0, 0, 0);
        A0 = __builtin_amdgcn_mfma_f32_16x16x32_bf16(af0[1], x1, A0, 0, 0, 0);
        A1 = __builtin_amdgcn_mfma_f32_16x16x32_bf16(af1[1], x1, A1, 0, 0, 0);
        char* hb = (char*)Hs + (size_t)(t & 1) * (16 * 264 * 2);  // this step's h buffer
        if (t > 0) {
            uint tg = (uint)(t - 1);
            const u64* src = hbuf + ((size_t)((t - 1) & 1) << 13) + p * 2048 + tid * 4;
            u64 vv0, vv1, vv2, vv3;
            bool got = false;
            if (!broken) {
                // FAST poll: plain sc0 dwordx4 loads (L1-bypass, L2-served; atomic-stored
                // lines are in/refreshable-through the shared TCC per R6's FETCH evidence).
                u32x4 pa, pb;
                bool ok;
                int guard = 0;
                do {
                    asm volatile(
                        "global_load_dwordx4 %0, %2, off sc0\n\t"
                        "global_load_dwordx4 %1, %2, off offset:16 sc0\n\t"
                        "s_waitcnt vmcnt(0)"
                        : "=&v"(pa), "=&v"(pb)
                        : "v"(src)
                        : "memory");
                    uint m = ((pa.x >> 16) ^ tg) | ((pa.y >> 16) ^ tg)
                           | ((pa.z >> 16) ^ tg) | ((pa.w >> 16) ^ tg)
                           | ((pb.x >> 16) ^ tg) | ((pb.y >> 16) ^ tg)
                           | ((pb.z >> 16) ^ tg) | ((pb.w >> 16) ^ tg);
                    ok = (m == 0);
                } while (!__all(ok) && ++guard < 1024);
                got = __all(ok);
                if (got) {
                    vv0 = ((u64)pa.y << 32) | pa.x;
                    vv1 = ((u64)pa.w << 32) | pa.z;
                    vv2 = ((u64)pb.y << 32) | pb.x;
                    vv3 = ((u64)pb.w << 32) | pb.z;
                } else {
                    broken = true;  // sticky: this wave polls atomically from now on
                }
            }
            if (!got) {
                // Fallback: R6-proven atomic-load poll on the SAME cells.
                u64 w0, w1, w2, w3;
                bool ok;
                int guard = 0;
                do {
                    w0 = __hip_atomic_load(src + 0, __ATOMIC_RELAXED, __HIP_MEMORY_SCOPE_AGENT);
                    w1 = __hip_atomic_load(src + 1, __ATOMIC_RELAXED, __HIP_MEMORY_SCOPE_AGENT);
                    w2 = __hip_atomic_load(src + 2, __ATOMIC_RELAXED, __HIP_MEMORY_SCOPE_AGENT);
                    w3 = __hip_atomic_load(src + 3, __ATOMIC_RELAXED, __HIP_MEMORY_SCOPE_AGENT);
                    uint m = (((uint)(w0 >> 16) & 0xFFFFu) ^ tg) | (((uint)(w0 >> 48)) ^ tg);
                    m |= (((uint)(w1 >> 16) & 0xFFFFu) ^ tg) | (((uint)(w1 >> 48)) ^ tg);
                    m |= (((uint)(w2 >> 16) & 0xFFFFu) ^ tg) | (((uint)(w2 >> 48)) ^ tg);
                    m |= (((uint)(w3 >> 16) & 0xFFFFu) ^ tg) | (((uint)(w3 >> 48)) ^ tg);
                    ok = (m == 0);
                } while (!__all(ok) && ++guard < (1 << 14));
                vv0 = w0; vv1 = w1; vv2 = w2; vv3 = w3;
            }
            // Stage to LDS dbuf: idx=4*tid -> b=idx>>7, c=idx&127; cell c = units {2c,2c+1}.
            {
                int b = tid >> 5, c0 = (tid * 4) & 127;
                uint4 w;
                w.x = ((uint)vv0 & 0xFFFFu) | (((uint)(vv0 >> 32) & 0xFFFFu) << 16);
                w.y = ((uint)vv1 & 0xFFFFu) | (((uint)(vv1 >> 32) & 0xFFFFu) << 16);
                w.z = ((uint)vv2 & 0xFFFFu) | (((uint)(vv2 >> 32) & 0xFFFFu) << 16);
                w.w = ((uint)vv3 & 0xFFFFu) | (((uint)(vv3 >> 32) & 0xFFFFu) << 16);
                *(uint4*)(hb + b * 528 + c0 * 4) = w;
            }
            __syncthreads();  // the ONLY barrier per step (Hs dbuf makes the 2nd redundant)
            // h-part MFMAs: frag = Hs[t&1][row=l16][units s*32+quad*8 ..+8], both tiles.
#pragma unroll
            for (int s = 0; s < 8; ++s) {
                bf16x8 bh = *(const bf16x8*)(hb + l16 * 528 + s * 64 + quad * 16);
                A0 = __builtin_amdgcn_mfma_f32_16x16x32_bf16(af0[2 + s], bh, A0, 0, 0, 0);
                A1 = __builtin_amdgcn_mfma_f32_16x16x32_bf16(af1[2 + s], bh, A1, 0, 0, 0);
            }
        }
        // Epilogue: lane owns (u0,bb) and (u1,bb).
        float hv0, hv1;
        {
            float gi = A0[0] + bi0, gf = A0[1] + bf0, gg = A0[2] + bg0, go = A0[3] + bo0;
            float ii = sigmoidf_(gi), ff = sigmoidf_(gf), g2 = tanhf_(gg), oo = sigmoidf_(go);
            cs0 = ff * cs0 + ii * g2;
            hv0 = oo * tanhf_(cs0);
        }
        {
            float gi = A1[0] + bi1, gf = A1[1] + bf1, gg = A1[2] + bg1, go = A1[3] + bo1;
            float ii = sigmoidf_(gi), ff = sigmoidf_(gf), g2 = tanhf_(gg), oo = sigmoidf_(go);
            cs1 = ff * cs1 + ii * g2;
            hv1 = oo * tanhf_(cs1);
        }
        if (t == TC_ - 1) {
            hfin[u0 * 64 + bb] = hv0;
            hfin[u1 * 64 + bb] = hv1;
        } else {
            // Publish: pack unit pairs via shfl (quad gets quad+1's value, same l16);
            // ATOMIC stores (R6-proven visible to same-XCD consumers).
            ushort h0 = f2bf(hv0), h1 = f2bf(hv1);
            uint pr0 = ((uint)h0 & 0xFFFFu) | ((uint)__shfl((int)h0, (lane + 16) & 63) << 16);
            uint pr1 = ((uint)h1 & 0xFFFFu) | ((uint)__shfl((int)h1, (lane + 16) & 63) << 16);
            if ((quad & 1) == 0) {
                uint tg2 = ((uint)t) << 16;
                u64 w0 = (u64)((pr0 & 0xFFFFu) | tg2) | ((u64)((pr0 >> 16) | tg2) << 32);
                u64 w1 = (u64)((pr1 & 0xFFFFu) | tg2) | ((u64)((pr1 >> 16) | tg2) << 32);
                u64* dst = hbuf + ((size_t)(t & 1) << 13) + p * 2048 + l16 * 128;
                __hip_atomic_store(dst + pc, w0, __ATOMIC_RELAXED, __HIP_MEMORY_SCOPE_AGENT);
                __hip_atomic_store(dst + pc + 2, w1, __ATOMIC_RELAXED, __HIP_MEMORY_SCOPE_AGENT);
            }
        }
        // Prefetch next xt (fire after publish; lands during next poll).
        int tn = (t + 1 < TC_) ? t + 1 : t;
        const ushort* xpn = li + ((size_t)tn * 64 + bb) * 72 + quad * 8;
        x0 = *(const bf16x8*)xpn;
        x1 = *(const bf16x8*)(xpn + 32);
    }
}

// ---- Kernel 5: out[b][o] = h_final[:,b] . lin_w[o,:] + lin_b[o] ----
__global__ __launch_bounds__(64) void k_fin(const float* __restrict__ hfin, const float* __restrict__ lw,
                                            const float* __restrict__ lb, float* __restrict__ out) {
    int o = blockIdx.x, b = threadIdx.x;
    float acc = lb[o];
    const float* wp = lw + o * 256;
#pragma unroll 4
    for (int u2 = 0; u2 < 256; ++u2) acc += hfin[u2 * 64 + b] * wp[u2];
    out[b * 10 + o] = acc;
}

extern "C" void kernel_launch(void* const* d_in, const int* in_sizes, int n_in,
                              void* d_out, int out_size, void* d_ws, size_t ws_size,
                              hipStream_t stream) {
    const float* in  = (const float*)d_in[0];
    // d_in[1] ("r") unused
    const float* cw  = (const float*)d_in[2];
    const float* cb  = (const float*)d_in[3];
    const float* wih = (const float*)d_in[4];
    const float* whh = (const float*)d_in[5];
    const float* bih = (const float*)d_in[6];
    const float* bhh = (const float*)d_in[7];
    const float* lw  = (const float*)d_in[8];
    const float* lb  = (const float*)d_in[9];
    float* out = (float*)d_out;

    char* ws = (char*)d_ws;
    float*  sq   = (float*)(ws + 0);          // 32768 B
    u64*    hbuf = (u64*)(ws + 32768);        // 131072 B: 2 parity x (4 pods x 2048 cells) x 8B
    float*  bias = (float*)(ws + 163840);     // 4096 B
    float*  hfin = (float*)(ws + 167936);     // 65536 B  [u][b] fp32
    ushort* wbf  = (ushort*)(ws + 233472);    // 655360 B [g2][16][320] bf16
    ushort* li   = (ushort*)(ws + 888832);    // 9418752 B [tc][b][72] bf16

    hipMemsetAsync(sq, 0, 32768, stream);
    hipMemsetAsync(hbuf, 0xFF, 131072, stream);  // tag fields -> 0xFFFF, never a valid step

    k_sqsum<<<1024, 128, 0, stream>>>(in, sq);
    k_prep<<<1280, 256, 0, stream>>>(wih, whh, bih, bhh, wbf, bias);
    k_conv<<<2048, 256, 0, stream>>>(in, cw, cb, sq, li);
    // 32 blocks: pod p = blockIdx%8 (XCD under round-robin dispatch), q = blockIdx/8.
    // Pods live on XCDs 0-3 (4 same-XCD blocks each); blocks with p>=4 exit at once.
    k_scan<<<32, 512, 0, stream>>>(li, wbf, bias, hbuf, hfin);
    k_fin<<<10, 64, 0, stream>>>(hfin, lw, lb, out);
}